// Round 6
// baseline (17396.121 us; speedup 1.0000x reference)
//
#include <hip/hip_runtime.h>
#include <hip/hip_bf16.h>

typedef __hip_bfloat16 bf16;
typedef __attribute__((ext_vector_type(8))) short short8;
typedef __attribute__((ext_vector_type(4))) float f32x4;
typedef unsigned long long u64;

#define N_ 8
#define B_ 64
#define T_ 256
#define IN_ 64
#define H_ 512
#define G4_ 2048
#define M_ 512
#define O_ 7

__device__ __forceinline__ float sigf(float x) { return 1.0f / (1.0f + __expf(-x)); }
__device__ __forceinline__ float tanhfast(float x) { return 2.0f / (1.0f + __expf(-2.0f * x)) - 1.0f; }
__device__ __forceinline__ float leaky(float x) { return x > 0.f ? x : 0.2f * x; }

// 16-byte h-load that bypasses L1+L2 (agent-scope relaxed atomics -> sc0 sc1,
// served at the coherent LLC). Used for ALL reads of mutable cross-block data.
union HU { u64 u[2]; short8 s; };
__device__ __forceinline__ short8 ldh(const bf16* p) {
  HU x;
  x.u[0] = __hip_atomic_load((const u64*)p,       __ATOMIC_RELAXED, __HIP_MEMORY_SCOPE_AGENT);
  x.u[1] = __hip_atomic_load((const u64*)(p + 4), __ATOMIC_RELAXED, __HIP_MEMORY_SCOPE_AGENT);
  return x.s;
}
// paired bf16 store, L2-bypassing (4-byte agent-scope relaxed atomic store)
__device__ __forceinline__ void sth2(bf16* p, float a, float b) {
  bf16 x = __float2bfloat16(a), y = __float2bfloat16(b);
  unsigned v = ((unsigned)(*(unsigned short*)&y) << 16) | (unsigned)(*(unsigned short*)&x);
  __hip_atomic_store((unsigned*)p, v, __ATOMIC_RELAXED, __HIP_MEMORY_SCOPE_AGENT);
}

// ---------------- convert fp32 -> bf16 ----------------
__global__ void cvt_kernel(const float* __restrict__ src, bf16* __restrict__ dst, int n4) {
  for (int i = blockIdx.x * blockDim.x + threadIdx.x; i < n4; i += gridDim.x * blockDim.x) {
    float4 v = ((const float4*)src)[i];
    bf16 t0 = __float2bfloat16(v.x), t1 = __float2bfloat16(v.y);
    bf16 t2 = __float2bfloat16(v.z), t3 = __float2bfloat16(v.w);
    ushort4 o;
    o.x = *(unsigned short*)&t0; o.y = *(unsigned short*)&t1;
    o.z = *(unsigned short*)&t2; o.w = *(unsigned short*)&t3;
    ((ushort4*)dst)[i] = o;
  }
}

// ---------------- K1: z = leaky(x@Win^T + bin)*10 ----------------
__global__ void input_kernel(const float* __restrict__ x, const float* __restrict__ Win,
                             const float* __restrict__ bin, bf16* __restrict__ z) {
  int bid = blockIdx.x;
  int t = bid >> 6;
  int b = bid & 63;
  __shared__ float xr[IN_];
  int tid = threadIdx.x;
  if (tid < IN_) xr[tid] = x[((size_t)b * T_ + t) * IN_ + tid];
  __syncthreads();
  for (int h = tid; h < H_; h += 256) {
    const float* w = Win + (size_t)h * IN_;
    float s = bin[h];
#pragma unroll 16
    for (int i = 0; i < IN_; ++i) s += xr[i] * w[i];
    s = (s > 0.f ? s : 0.2f * s) * 10.f;
    z[((size_t)t * B_ + b) * H_ + h] = __float2bfloat16(s);
  }
}

// ---------------- per-model grid barrier ----------------
// RELEASE add (orders the h-stores before the counter bump), RELAXED spin
// (no buffer_inv per poll — the round-5 killer). Data freshness comes from
// h traffic bypassing L2 entirely, not from cache invalidation.
__device__ __forceinline__ void gbar(unsigned* ctr, unsigned target) {
  __syncthreads();
  if (threadIdx.x == 0) {
    __hip_atomic_fetch_add(ctr, 1u, __ATOMIC_RELEASE, __HIP_MEMORY_SCOPE_AGENT);
    while (__hip_atomic_load(ctr, __ATOMIC_RELAXED, __HIP_MEMORY_SCOPE_AGENT) < target) {
      __builtin_amdgcn_s_sleep(2);
    }
  }
  __syncthreads();
}

// ---------------- K2: persistent weight-stationary LSTM scan + fused head ----------------
// 256 blocks x 512 thr, 1 block/CU. Block (n = bid&7, blk = bid>>3): 16 hidden/M
// units of model n (model-per-XCD swizzle for L2 locality; correctness does not
// depend on placement). Wave w = 2g+m holds (gate g, matrix m) B-fragments for
// both layers in registers. 3-stage pipeline: L0(t=s), L1(t=s-1), HF(t=s-2:
// head1 MFMA + in-register head2 + atomicAdd to out). One barrier per step.
__global__ void __launch_bounds__(512, 2) scan_kernel(
    const bf16* __restrict__ z,
    const bf16* __restrict__ Wih0, const bf16* __restrict__ Whh0,
    const float* __restrict__ bih0, const float* __restrict__ bhh0,
    const bf16* __restrict__ Wih1, const bf16* __restrict__ Whh1,
    const float* __restrict__ bih1, const float* __restrict__ bhh1,
    const bf16* __restrict__ Wh1, const float* __restrict__ bh1,
    const float* __restrict__ Wh2, const float* __restrict__ bh2,
    bf16* __restrict__ h0buf, bf16* __restrict__ h1buf,
    float* __restrict__ out, unsigned* __restrict__ barctr)
{
  __shared__ float S0[8][B_][16];
  __shared__ float S1[8][B_][16];
  __shared__ float c0s[B_ * 16];
  __shared__ float c1s[B_ * 16];

  const int tid = threadIdx.x;
  const int lane = tid & 63;
  const int w = tid >> 6;      // 0..7
  const int m = w & 1;         // 0: ih-matrix, 1: hh-matrix
  const int g = w >> 1;        // gate 0..3 (i,f,g,o)
  const int q = lane >> 4;
  const int cl = lane & 15;
  const int bid = blockIdx.x;
  const int n = bid & 7;       // model-per-XCD swizzle
  const int blk = bid >> 3;    // 0..31
  const int ub = blk << 4;

  const size_t NBH = (size_t)N_ * B_ * H_;

  // ---- one-time weight preload into registers (compiler may use AGPRs) ----
  const size_t wrow = (size_t)n * G4_ * H_ + (size_t)(g * H_ + ub + cl) * H_ + q * 8;
  const bf16* WL0 = (m == 0 ? Wih0 : Whh0) + wrow;
  const bf16* WL1 = (m == 0 ? Wih1 : Whh1) + wrow;
  short8 wl0[16], wl1[16];
#pragma unroll
  for (int kk = 0; kk < 16; ++kk) {
    wl0[kk] = *(const short8*)(WL0 + kk * 32);
    wl1[kk] = *(const short8*)(WL1 + kk * 32);
  }
  const int bi = n * G4_ + g * H_ + ub + cl;
  const float bs0 = (m == 0) ? (bih0[bi] + bhh0[bi]) : 0.f;
  const float bs1 = (m == 0) ? (bih1[bi] + bhh1[bi]) : 0.f;
  const float bh1v = bh1[n * M_ + ub + cl];
  float w2v[O_], b2v[O_];
#pragma unroll
  for (int o = 0; o < O_; ++o) {
    w2v[o] = Wh2[(size_t)n * O_ * M_ + o * M_ + ub + cl];
    b2v[o] = bh2[n * O_ + o];
  }

  for (int e = tid; e < B_ * 16; e += 512) { c0s[e] = 0.f; c1s[e] = 0.f; }

  unsigned* ctr = barctr + n * 32;
  unsigned target = 0;

  for (int s = 0; s < T_ + 2; ++s) {
    const bool doL0 = (s < T_);
    const bool doL1 = (s >= 1 && s <= T_);
    const bool doHF = (s >= 2);

    // ---- L0: this wave's (matrix,gate) partial, 4 batch strips ----
    if (doL0) {
      if (m == 0) {
        const bf16* A = z + (size_t)s * B_ * H_;   // read-only: normal cached loads
#pragma unroll
        for (int strip = 0; strip < 4; ++strip) {
          f32x4 acc = (f32x4){bs0, bs0, bs0, bs0};
          const bf16* Ap = A + (size_t)(strip * 16 + cl) * H_ + q * 8;
#pragma unroll
          for (int kk = 0; kk < 16; ++kk) {
            short8 a = *(const short8*)(Ap + kk * 32);
            acc = __builtin_amdgcn_mfma_f32_16x16x32_bf16(a, wl0[kk], acc, 0, 0, 0);
          }
#pragma unroll
          for (int r = 0; r < 4; ++r) S0[w][strip * 16 + q * 4 + r][cl] = acc[r];
        }
      } else {
        const bf16* A = h0buf + (size_t)((s & 1) ^ 1) * NBH + (size_t)n * B_ * H_;
#pragma unroll
        for (int strip = 0; strip < 4; ++strip) {
          f32x4 acc = (f32x4){bs0, bs0, bs0, bs0};
          const bf16* Ap = A + (size_t)(strip * 16 + cl) * H_ + q * 8;
#pragma unroll
          for (int kk = 0; kk < 16; ++kk) {
            short8 a = ldh(Ap + kk * 32);
            acc = __builtin_amdgcn_mfma_f32_16x16x32_bf16(a, wl0[kk], acc, 0, 0, 0);
          }
#pragma unroll
          for (int r = 0; r < 4; ++r) S0[w][strip * 16 + q * 4 + r][cl] = acc[r];
        }
      }
    }
    // ---- L1 ----
    if (doL1) {
      const int t = s - 1;
      const bf16* A = (m == 0)
          ? h0buf + (size_t)(t & 1) * NBH + (size_t)n * B_ * H_
          : h1buf + (size_t)((t & 1) ^ 1) * NBH + (size_t)n * B_ * H_;
#pragma unroll
      for (int strip = 0; strip < 4; ++strip) {
        f32x4 acc = (f32x4){bs1, bs1, bs1, bs1};
        const bf16* Ap = A + (size_t)(strip * 16 + cl) * H_ + q * 8;
#pragma unroll
        for (int kk = 0; kk < 16; ++kk) {
          short8 a = ldh(Ap + kk * 32);
          acc = __builtin_amdgcn_mfma_f32_16x16x32_bf16(a, wl1[kk], acc, 0, 0, 0);
        }
#pragma unroll
        for (int r = 0; r < 4; ++r) S1[w][strip * 16 + q * 4 + r][cl] = acc[r];
      }
    }
    // ---- HF: head for t=s-2. Wave w covers batches w*16..w*16+15, this
    // block's 16 m-units; head2 folded in-register, atomicAdd into out. ----
    if (doHF && w < 4) {
      const int tH = s - 2;
      f32x4 aH = (f32x4){bh1v, bh1v, bh1v, bh1v};
      const bf16* hsrc = h1buf + (size_t)(tH & 1) * NBH + (size_t)n * B_ * H_;
      const bf16* w1p = Wh1 + (size_t)n * M_ * H_ + (size_t)(ub + cl) * H_ + q * 8;
      const bf16* ap = hsrc + (size_t)(w * 16 + cl) * H_ + q * 8;
#pragma unroll
      for (int kk = 0; kk < 16; ++kk) {
        short8 a = ldh(ap + kk * 32);
        short8 b = *(const short8*)(w1p + kk * 32);   // Wh1: read-only, cached
        aH = __builtin_amdgcn_mfma_f32_16x16x32_bf16(a, b, aH, 0, 0, 0);
      }
#pragma unroll
      for (int r = 0; r < 4; ++r) {
        const float l = leaky(aH[r]);
        float p[O_];
#pragma unroll
        for (int o = 0; o < O_; ++o) p[o] = l * w2v[o];
#pragma unroll
        for (int o = 0; o < O_; ++o) {
          p[o] += __shfl_xor(p[o], 1, 64);
          p[o] += __shfl_xor(p[o], 2, 64);
          p[o] += __shfl_xor(p[o], 4, 64);
          p[o] += __shfl_xor(p[o], 8, 64);
        }
        if (cl == 0) {
          const int b = w * 16 + q * 4 + r;
          float* op = out + (((size_t)n * B_ + b) * T_ + tH) * O_;
#pragma unroll
          for (int o = 0; o < O_; ++o) {
            float v = p[o] + (blk == 0 ? b2v[o] : 0.f);
            atomicAdd(op + o, v);
          }
        }
      }
    }

    __syncthreads();

    // ---- elementwise: gates = ih+hh slots, update c (LDS), write h (bypass) ----
    {
      const int row = tid >> 3;
      const int ulp = (tid & 7) * 2;
      const int ci = row * 16 + ulp;
      if (doL0) {
        float2 v0 = *(const float2*)&S0[0][row][ulp], v1 = *(const float2*)&S0[1][row][ulp];
        float2 v2 = *(const float2*)&S0[2][row][ulp], v3 = *(const float2*)&S0[3][row][ulp];
        float2 v4 = *(const float2*)&S0[4][row][ulp], v5 = *(const float2*)&S0[5][row][ulp];
        float2 v6 = *(const float2*)&S0[6][row][ulp], v7 = *(const float2*)&S0[7][row][ulp];
        float cA = c0s[ci], cB = c0s[ci + 1];
        float cnA = sigf(v2.x + v3.x) * cA + sigf(v0.x + v1.x) * tanhfast(v4.x + v5.x);
        float cnB = sigf(v2.y + v3.y) * cB + sigf(v0.y + v1.y) * tanhfast(v4.y + v5.y);
        c0s[ci] = cnA; c0s[ci + 1] = cnB;
        bf16* h0out = h0buf + (size_t)(s & 1) * NBH + (size_t)n * B_ * H_;
        sth2(h0out + (size_t)row * H_ + ub + ulp,
             sigf(v6.x + v7.x) * tanhfast(cnA), sigf(v6.y + v7.y) * tanhfast(cnB));
      }
      if (doL1) {
        const int t = s - 1;
        float2 v0 = *(const float2*)&S1[0][row][ulp], v1 = *(const float2*)&S1[1][row][ulp];
        float2 v2 = *(const float2*)&S1[2][row][ulp], v3 = *(const float2*)&S1[3][row][ulp];
        float2 v4 = *(const float2*)&S1[4][row][ulp], v5 = *(const float2*)&S1[5][row][ulp];
        float2 v6 = *(const float2*)&S1[6][row][ulp], v7 = *(const float2*)&S1[7][row][ulp];
        float cA = c1s[ci], cB = c1s[ci + 1];
        float cnA = sigf(v2.x + v3.x) * cA + sigf(v0.x + v1.x) * tanhfast(v4.x + v5.x);
        float cnB = sigf(v2.y + v3.y) * cB + sigf(v0.y + v1.y) * tanhfast(v4.y + v5.y);
        c1s[ci] = cnA; c1s[ci + 1] = cnB;
        bf16* h1out = h1buf + (size_t)(t & 1) * NBH + (size_t)n * B_ * H_;
        sth2(h1out + (size_t)row * H_ + ub + ulp,
             sigf(v6.x + v7.x) * tanhfast(cnA), sigf(v6.y + v7.y) * tanhfast(cnB));
      }
    }

    target += 32;
    gbar(ctr, target);
  }
}

extern "C" void kernel_launch(void* const* d_in, const int* in_sizes, int n_in,
                              void* d_out, int out_size, void* d_ws, size_t ws_size,
                              hipStream_t stream) {
  (void)in_sizes; (void)n_in; (void)ws_size;
  const float* x    = (const float*)d_in[0];
  const float* Win  = (const float*)d_in[1];
  const float* bin  = (const float*)d_in[2];
  const float* Wih0 = (const float*)d_in[3];
  const float* Whh0 = (const float*)d_in[4];
  const float* bih0 = (const float*)d_in[5];
  const float* bhh0 = (const float*)d_in[6];
  const float* Wih1 = (const float*)d_in[7];
  const float* Whh1 = (const float*)d_in[8];
  const float* bih1 = (const float*)d_in[9];
  const float* bhh1 = (const float*)d_in[10];
  const float* Wh1  = (const float*)d_in[11];
  const float* bh1  = (const float*)d_in[12];
  const float* Wh2  = (const float*)d_in[13];
  const float* bh2  = (const float*)d_in[14];

  const size_t WLSTM = (size_t)N_ * G4_ * H_;
  const size_t WH1   = (size_t)N_ * M_ * H_;

  char* ws = (char*)d_ws;
  size_t off = 0;
  bf16* z      = (bf16*)(ws + off); off += (size_t)T_ * B_ * H_ * sizeof(bf16);
  bf16* Wih0b  = (bf16*)(ws + off); off += WLSTM * sizeof(bf16);
  bf16* Whh0b  = (bf16*)(ws + off); off += WLSTM * sizeof(bf16);
  bf16* Wih1b  = (bf16*)(ws + off); off += WLSTM * sizeof(bf16);
  bf16* Whh1b  = (bf16*)(ws + off); off += WLSTM * sizeof(bf16);
  bf16* Wh1b   = (bf16*)(ws + off); off += WH1 * sizeof(bf16);
  bf16* h0buf  = (bf16*)(ws + off); off += 2 * (size_t)N_ * B_ * H_ * sizeof(bf16);
  bf16* h1buf  = (bf16*)(ws + off); off += 2 * (size_t)N_ * B_ * H_ * sizeof(bf16);
  unsigned* barctr = (unsigned*)(ws + off); off += 8 * 32 * sizeof(unsigned);

  // zero h state + barrier counters; zero output (accumulated via atomicAdd)
  hipMemsetAsync(h0buf, 0, (char*)(barctr + 8 * 32) - (char*)h0buf, stream);
  hipMemsetAsync(d_out, 0, (size_t)out_size * sizeof(float), stream);

  cvt_kernel<<<dim3(2048), dim3(256), 0, stream>>>(Wih0, Wih0b, (int)(WLSTM / 4));
  cvt_kernel<<<dim3(2048), dim3(256), 0, stream>>>(Whh0, Whh0b, (int)(WLSTM / 4));
  cvt_kernel<<<dim3(2048), dim3(256), 0, stream>>>(Wih1, Wih1b, (int)(WLSTM / 4));
  cvt_kernel<<<dim3(2048), dim3(256), 0, stream>>>(Whh1, Whh1b, (int)(WLSTM / 4));
  cvt_kernel<<<dim3(1024), dim3(256), 0, stream>>>(Wh1, Wh1b, (int)(WH1 / 4));

  input_kernel<<<dim3(T_ * B_), dim3(256), 0, stream>>>(x, Win, bin, z);

  scan_kernel<<<dim3(256), dim3(512), 0, stream>>>(
      z, Wih0b, Whh0b, bih0, bhh0, Wih1b, Whh1b, bih1, bhh1,
      Wh1b, bh1, Wh2, bh2, h0buf, h1buf, (float*)d_out, barctr);
}